// Round 8
// baseline (343.317 us; speedup 1.0000x reference)
//
#include <hip/hip_runtime.h>
#include <hip/hip_bf16.h>
#include <hip/hip_cooperative_groups.h>
#include <math.h>

namespace cg = cooperative_groups;

// Problem constants
#define BB 8
#define CC 256
#define NN 1024     // H*W
#define HEADS 8
#define HDIM 32
#define NGRP 8

using bf16x8 = __attribute__((ext_vector_type(8))) short;
using f32x4  = __attribute__((ext_vector_type(4))) float;

#if __has_builtin(__builtin_amdgcn_exp2f)
#define EXP2(x) __builtin_amdgcn_exp2f(x)
#else
#define EXP2(x) exp2f(x)
#endif

// 1/sqrt(32) * log2(e): folded into Q so softmax exp is native v_exp_f32
#define SCL_Q_LOG2E 0.2550348892803828f

static __device__ __forceinline__ ushort f2bf(float x) {
  union { __hip_bfloat16 b; ushort u; } c;
  c.b = __float2bfloat16(x);   // RNE
  return c.u;
}

union FragU { ushort4 u[2]; bf16x8 f; };

// ---------------------------------------------------------------------------
// Conv tile body (R7-verified): 64(o) x 64(n), BK=64, 4 waves 2x2, each wave
// 32x32 via 2x2 frags of 16x16x32. W staged from fp32 with inline bf16 cast.
// MODE 0 -> qT2/kT2 [bh][dh][n][16d] + vN [bh][d][n] (LDS-bounced stores).
// MODE 1 -> bias + fp32 residual -> out.
// ---------------------------------------------------------------------------
template <int MODE>
static __device__ __forceinline__ void conv_tile(
    char* smem, const int t, const int b, const int o0, const int n0,
    const float* __restrict__ W32, const float* __restrict__ bias,
    const ushort* __restrict__ X, const float* __restrict__ xres,
    ushort* __restrict__ qT2, ushort* __restrict__ kT2,
    ushort* __restrict__ vN, float* __restrict__ out)
{
  const int w = t >> 6, l = t & 63;
  const int lg = l >> 4, lr = l & 15;
  const int wr = w >> 1, wc = w & 1;

  ushort (*Ws)[72] = (ushort(*)[72])smem;            // [o][k]
  ushort (*Xs)[72] = (ushort(*)[72])(smem + 9216);   // [n][k]

  f32x4 acc[2][2] = {};  // [ms(o)][ns(n)]
  const ushort* Xb = X + (size_t)b * 1024 * 256;

  for (int k0 = 0; k0 < 256; k0 += 64) {
    __syncthreads();
#pragma unroll
    for (int li = 0; li < 2; ++li) {
      const int id = t + (li << 8);       // 0..511
      const int rr = id >> 3, c8 = id & 7;
      const float* wsrc = W32 + (size_t)(o0 + rr) * 256 + k0 + c8 * 8;
      const float4 wa = *(const float4*)wsrc;
      const float4 wb = *(const float4*)(wsrc + 4);
      union { uint4 v; ushort s[8]; } wv;
      wv.s[0] = f2bf(wa.x); wv.s[1] = f2bf(wa.y); wv.s[2] = f2bf(wa.z); wv.s[3] = f2bf(wa.w);
      wv.s[4] = f2bf(wb.x); wv.s[5] = f2bf(wb.y); wv.s[6] = f2bf(wb.z); wv.s[7] = f2bf(wb.w);
      *(uint4*)&Ws[rr][c8 * 8] = wv.v;
      const uint4 xv = *(const uint4*)(Xb + (size_t)(n0 + rr) * 256 + k0 + c8 * 8);
      *(uint4*)&Xs[rr][c8 * 8] = xv;
    }
    __syncthreads();

    FragU af[2][2], xf[2][2];  // [ms|ns][kc]
#pragma unroll
    for (int i = 0; i < 2; ++i)
#pragma unroll
      for (int kc = 0; kc < 2; ++kc) {
        const ushort* p = &Ws[wr * 32 + i * 16 + lr][kc * 32 + lg * 4];
        af[i][kc].u[0] = *(const ushort4*)p;
        af[i][kc].u[1] = *(const ushort4*)(p + 16);
        const ushort* q = &Xs[wc * 32 + i * 16 + lr][kc * 32 + lg * 4];
        xf[i][kc].u[0] = *(const ushort4*)q;
        xf[i][kc].u[1] = *(const ushort4*)(q + 16);
      }
#pragma unroll
    for (int ms = 0; ms < 2; ++ms)
#pragma unroll
      for (int ns = 0; ns < 2; ++ns) {
        acc[ms][ns] = __builtin_amdgcn_mfma_f32_16x16x32_bf16(af[ms][0].f, xf[ns][0].f, acc[ms][ns], 0, 0, 0);
        acc[ms][ns] = __builtin_amdgcn_mfma_f32_16x16x32_bf16(af[ms][1].f, xf[ns][1].f, acc[ms][ns], 0, 0, 0);
      }
  }

  if (MODE == 0) {
    const int sec = o0 >> 8;               // 0=Q, 1=K, 2=V
    const int oin = o0 & 255;
    const float scl = (sec == 0) ? SCL_Q_LOG2E : 1.0f;
    ushort* Lp = &Xs[0][0];
    __syncthreads();
#pragma unroll
    for (int ms = 0; ms < 2; ++ms) {
      const int ob = o0 + wr * 32 + ms * 16 + lg * 4;
      const float4 b4 = *(const float4*)(bias + ob);
      const int ol = wr * 32 + ms * 16 + lg * 4;
#pragma unroll
      for (int ns = 0; ns < 2; ++ns) {
        const int nl = wc * 32 + ns * 16 + lr;
        Lp[(ol + 0) * 68 + nl] = f2bf((acc[ms][ns][0] + b4.x) * scl);
        Lp[(ol + 1) * 68 + nl] = f2bf((acc[ms][ns][1] + b4.y) * scl);
        Lp[(ol + 2) * 68 + nl] = f2bf((acc[ms][ns][2] + b4.z) * scl);
        Lp[(ol + 3) * 68 + nl] = f2bf((acc[ms][ns][3] + b4.w) * scl);
      }
    }
    __syncthreads();
    if (sec < 2) {
      ushort* dst = (sec == 0) ? qT2 : kT2;
      const int nl = t & 63, hd = t >> 6;
      const int hl = hd >> 1, dh = hd & 1;
      const int bh = b * 8 + (oin >> 5) + hl;
      union { uint4 v[2]; ushort s[16]; } o;
#pragma unroll
      for (int j = 0; j < 16; ++j)
        o.s[j] = Lp[(hl * 32 + dh * 16 + j) * 68 + nl];
      uint4* dp = (uint4*)(dst + (((size_t)bh * 2 + dh) * 1024 + n0 + nl) * 16);
      dp[0] = o.v[0];
      dp[1] = o.v[1];
    } else {
      const int r = t >> 2, p = t & 3;
      const int oo = oin + r, hh = oo >> 5, d0 = oo & 31;
      union { uint4 v[2]; ushort4 s[4]; } o;
#pragma unroll
      for (int j = 0; j < 4; ++j)
        o.s[j] = *(const ushort4*)&Lp[r * 68 + p * 16 + j * 4];
      uint4* dp = (uint4*)(vN + (((size_t)b * 8 + hh) * 32 + d0) * 1024 + n0 + p * 16);
      dp[0] = o.v[0];
      dp[1] = o.v[1];
    }
  } else {
#pragma unroll
    for (int ms = 0; ms < 2; ++ms) {
      const int ob = o0 + wr * 32 + ms * 16 + lg * 4;
      const float4 b4 = *(const float4*)(bias + ob);
#pragma unroll
      for (int ns = 0; ns < 2; ++ns) {
        const int n = n0 + wc * 32 + ns * 16 + lr;
        const size_t i0 = ((size_t)b * 256 + ob) * 1024 + n;
        out[i0]          = acc[ms][ns][0] + b4.x + xres[i0];
        out[i0 + 1024]   = acc[ms][ns][1] + b4.y + xres[i0 + 1024];
        out[i0 + 2048]   = acc[ms][ns][2] + b4.z + xres[i0 + 2048];
        out[i0 + 3072]   = acc[ms][ns][3] + b4.w + xres[i0 + 3072];
      }
    }
  }
}

// ---------------------------------------------------------------------------
// Single fused cooperative kernel. Grid 512 x 256 thr, 2 blocks/CU.
// P0 gn-stats -> P1 gn-apply+transpose -> P2 qkv conv -> P3 attn -> P4 out.
// ---------------------------------------------------------------------------
__global__ __launch_bounds__(256, 2) void fused_kernel(
    const float* __restrict__ x, const float* __restrict__ gns,
    const float* __restrict__ gnb, const float* __restrict__ wqkv,
    const float* __restrict__ bqkv, const float* __restrict__ wout,
    const float* __restrict__ bout, float* __restrict__ out,
    ushort* __restrict__ hT, ushort* __restrict__ qT2,
    ushort* __restrict__ kT2, ushort* __restrict__ vN,
    ushort* __restrict__ aoT, float2* __restrict__ part)
{
  cg::grid_group grid = cg::this_grid();
  __shared__ __align__(16) char smem[18432];
  __shared__ float rs[4], rss[4];
  __shared__ float2 gstat[2];
  const int t = threadIdx.x;
  const int bid = blockIdx.x;
  const int wid = t >> 6, lane = t & 63;

  // ---------------- P0: GN partial stats (1024 chunks of 2048 floats) ------
#pragma unroll
  for (int ci = 0; ci < 2; ++ci) {
    const int c = bid + ci * 512;
    const float4* src = (const float4*)x + (size_t)c * 512;
    const float4 a = src[t], b2 = src[t + 256];
    float s  = a.x + a.y + a.z + a.w + b2.x + b2.y + b2.z + b2.w;
    float ss = a.x*a.x + a.y*a.y + a.z*a.z + a.w*a.w
             + b2.x*b2.x + b2.y*b2.y + b2.z*b2.z + b2.w*b2.w;
#pragma unroll
    for (int off = 32; off > 0; off >>= 1) {
      s  += __shfl_down(s, off);
      ss += __shfl_down(ss, off);
    }
    __syncthreads();
    if (lane == 0) { rs[wid] = s; rss[wid] = ss; }
    __syncthreads();
    if (t == 0) {
      float2 o;
      o.x = rs[0] + rs[1] + rs[2] + rs[3];
      o.y = rss[0] + rss[1] + rss[2] + rss[3];
      part[c] = o;
    }
  }
  grid.sync();

  // ---------------- P1: GN apply + transpose -> hT[b][n][c] ---------------
  {
    const int b = bid >> 6;
    const int cq = (bid >> 4) & 3;
    const int c0 = cq << 6, n0 = (bid & 15) << 6;
    ushort* Ls = (ushort*)smem;  // [n][c] pitch 68

    if (t < 32) {
      const int gsel = t >> 4, ci = t & 15;
      const float2 pp = part[((b * 8) + (cq << 1) + gsel) * 16 + ci];
      float s = pp.x, ss = pp.y;
#pragma unroll
      for (int off = 8; off > 0; off >>= 1) {
        s  += __shfl_down(s, off, 16);
        ss += __shfl_down(ss, off, 16);
      }
      if (ci == 0) {
        const float mean = s * (1.f / 32768.f);
        const float var = ss * (1.f / 32768.f) - mean * mean;
        float2 o; o.x = mean; o.y = rsqrtf(var + 1e-5f);
        gstat[gsel] = o;
      }
    }
    __syncthreads();

#pragma unroll
    for (int li = 0; li < 4; ++li) {
      const int id = t + (li << 8);          // 0..1023
      const int row = id >> 4, col4 = id & 15;
      const int c = c0 + row;
      const float2 st = gstat[row >> 5];
      const float sc = gns[c] * st.y;
      const float sh = gnb[c] - st.x * sc;
      const float4 v = *(const float4*)(x + ((size_t)b * CC + c) * NN + n0 + col4 * 4);
      const int nb = col4 * 4;
      Ls[(nb + 0) * 68 + row] = f2bf(v.x * sc + sh);
      Ls[(nb + 1) * 68 + row] = f2bf(v.y * sc + sh);
      Ls[(nb + 2) * 68 + row] = f2bf(v.z * sc + sh);
      Ls[(nb + 3) * 68 + row] = f2bf(v.w * sc + sh);
    }
    __syncthreads();
#pragma unroll
    for (int li = 0; li < 2; ++li) {
      const int id = t + (li << 8);          // 0..511
      const int nR = id >> 3, cP = id & 7;
      union { uint4 v; ushort4 s[2]; } ov;
      ov.s[0] = *(const ushort4*)&Ls[nR * 68 + cP * 8];
      ov.s[1] = *(const ushort4*)&Ls[nR * 68 + cP * 8 + 4];
      *(uint4*)(hT + ((size_t)b * NN + n0 + nR) * CC + c0 + cP * 8) = ov.v;
    }
  }
  grid.sync();

  // ---------------- P2: QKV conv (3 tiles per block) ----------------------
  for (int u = bid; u < 1536; u += 512) {
    const int nx = u & 15;
    const int v = u >> 4;          // 0..95
    const int b = v / 12;
    const int oy = v - b * 12;
    conv_tile<0>(smem, t, b, oy << 6, nx << 6, wqkv, bqkv, hT, nullptr,
                 qT2, kT2, vN, nullptr);
  }
  grid.sync();

  // ---------------- P3: attention (128 q per block, 4 waves) --------------
  {
    const int w = t >> 6, l = t & 63;
    const int lg = l >> 4, lr = l & 15;
    const int bh = bid >> 3;
    const int b = bh >> 3, hh = bh & 7;
    const int qb = (bid & 7) << 7;

    ushort* Ks = (ushort*)smem;            // [64][40]
    ushort* Vs = (ushort*)(smem + 10240);  // [32][72]

    const ushort* Qb2 = qT2 + (size_t)bh * 2 * 1024 * 16;
    const ushort* Kb2 = kT2 + (size_t)bh * 2 * 1024 * 16;
    const ushort* Vbh = vN + (size_t)bh * 32 * 1024;

    FragU qf[2];
#pragma unroll
    for (int qh = 0; qh < 2; ++qh) {
      const int qn = qb + w * 32 + qh * 16 + lr;
      qf[qh].u[0] = *(const ushort4*)(Qb2 + (size_t)qn * 16 + lg * 4);
      qf[qh].u[1] = *(const ushort4*)(Qb2 + (size_t)(1024 + qn) * 16 + lg * 4);
    }

    f32x4 accO[2][2] = {};          // [qh][dt]
    float lsum0 = 0.f, lsum1 = 0.f;

    // Staging (256 thr): K 64x32 (1 uint4/thr), V 32x64 (1 uint4/thr).
    const int km = t >> 2, ksel = t & 3, kdh = ksel >> 1, khalf = ksel & 1;
    const ushort* kbase = Kb2 + ((size_t)kdh * 1024 + km) * 16 + khalf * 8;
    const int vd = t >> 3, vm = (t & 7) * 8;
    const ushort* vbase = Vbh + (size_t)vd * 1024 + vm;

    uint4 kr = *(const uint4*)kbase;
    uint4 vr = *(const uint4*)vbase;

    for (int m0 = 0; m0 < NN; m0 += 64) {
      __syncthreads();
      *(uint4*)&Ks[km * 40 + kdh * 16 + khalf * 8] = kr;
      *(uint4*)&Vs[vd * 72 + vm] = vr;
      __syncthreads();
      if (m0 + 64 < NN) {
        kr = *(const uint4*)(kbase + (size_t)(m0 + 64) * 16);
        vr = *(const uint4*)(vbase + (m0 + 64));
      }

      // S^T = K . Q^T : 4 m-subtiles x 2 q-halves (K-frag shared).
      f32x4 s[4][2];
#pragma unroll
      for (int ms = 0; ms < 4; ++ms) {
        FragU kf;
        const ushort* kp = &Ks[(ms * 16 + lr) * 40 + lg * 4];
        kf.u[0] = *(const ushort4*)kp;
        kf.u[1] = *(const ushort4*)(kp + 16);
        f32x4 z = {0.f, 0.f, 0.f, 0.f};
        s[ms][0] = __builtin_amdgcn_mfma_f32_16x16x32_bf16(kf.f, qf[0].f, z, 0, 0, 0);
        s[ms][1] = __builtin_amdgcn_mfma_f32_16x16x32_bf16(kf.f, qf[1].f, z, 0, 0, 0);
      }

      // p = exp2(S); accumulate l; pack bf16 B-frags. No cross-lane ops.
      bf16x8 pb[2][2];  // [qh][mc]
#pragma unroll
      for (int mc = 0; mc < 2; ++mc) {
        bf16x8 f0, f1;
#pragma unroll
        for (int r = 0; r < 4; ++r) {
          const float a0 = EXP2(s[2 * mc][0][r]);
          const float a1 = EXP2(s[2 * mc + 1][0][r]);
          const float b0 = EXP2(s[2 * mc][1][r]);
          const float b1 = EXP2(s[2 * mc + 1][1][r]);
          lsum0 += a0 + a1;
          lsum1 += b0 + b1;
          f0[r] = (short)f2bf(a0); f0[r + 4] = (short)f2bf(a1);
          f1[r] = (short)f2bf(b0); f1[r + 4] = (short)f2bf(b1);
        }
        pb[0][mc] = f0;
        pb[1][mc] = f1;
      }

      // PV: O^T[d][n] += V[d][m] . P^T[m][n] (V-frag shared by both qh).
#pragma unroll
      for (int dt = 0; dt < 2; ++dt) {
#pragma unroll
        for (int mc = 0; mc < 2; ++mc) {
          FragU vf;
          const ushort* vpp = &Vs[(dt * 16 + lr) * 72 + mc * 32 + lg * 4];
          vf.u[0] = *(const ushort4*)vpp;
          vf.u[1] = *(const ushort4*)(vpp + 16);
          accO[0][dt] = __builtin_amdgcn_mfma_f32_16x16x32_bf16(vf.f, pb[0][mc], accO[0][dt], 0, 0, 0);
          accO[1][dt] = __builtin_amdgcn_mfma_f32_16x16x32_bf16(vf.f, pb[1][mc], accO[1][dt], 0, 0, 0);
        }
      }
    }

    lsum0 += __shfl_xor(lsum0, 16); lsum0 += __shfl_xor(lsum0, 32);
    lsum1 += __shfl_xor(lsum1, 16); lsum1 += __shfl_xor(lsum1, 32);
    const float inv0 = 1.f / lsum0, inv1 = 1.f / lsum1;

    // Epilogue: bounce 128 x 32 tile through LDS, pitch 36.
    ushort* Lb = (ushort*)smem;
    __syncthreads();
#pragma unroll
    for (int dt = 0; dt < 2; ++dt)
#pragma unroll
      for (int r = 0; r < 4; ++r) {
        Lb[(w * 32 + lr) * 36 + dt * 16 + lg * 4 + r]      = f2bf(accO[0][dt][r] * inv0);
        Lb[(w * 32 + 16 + lr) * 36 + dt * 16 + lg * 4 + r] = f2bf(accO[1][dt][r] * inv1);
      }
    __syncthreads();
    {
      const int nl = t >> 1, pp = (t & 1) * 16;
      union { uint4 v[2]; ushort4 s[4]; } o;
#pragma unroll
      for (int j = 0; j < 4; ++j)
        o.s[j] = *(const ushort4*)&Lb[nl * 36 + pp + j * 4];
      uint4* dp = (uint4*)(aoT + ((size_t)b * 1024 + qb + nl) * 256 + hh * 32 + pp);
      dp[0] = o.v[0];
      dp[1] = o.v[1];
    }
  }
  grid.sync();

  // ---------------- P4: out conv + residual -------------------------------
  {
    const int nx = bid & 15, oy = (bid >> 4) & 3, b = bid >> 6;
    conv_tile<1>(smem, t, b, oy << 6, nx << 6, wout, bout, aoT, x,
                 nullptr, nullptr, nullptr, out);
  }
}

// ---------------------------------------------------------------------------
// Launch. ws layout (MB offsets):
//   hT @0 | qT2 @4 | kT2 @8 | vN @12 | aoT @16 | part @20 (8 KB)
// ---------------------------------------------------------------------------
extern "C" void kernel_launch(void* const* d_in, const int* in_sizes, int n_in,
                              void* d_out, int out_size, void* d_ws, size_t ws_size,
                              hipStream_t stream)
{
  const float* x    = (const float*)d_in[0];
  const float* gns  = (const float*)d_in[1];
  const float* gnb  = (const float*)d_in[2];
  const float* wqkv = (const float*)d_in[3];
  const float* bqkv = (const float*)d_in[4];
  const float* wout = (const float*)d_in[5];
  const float* bout = (const float*)d_in[6];
  float* out = (float*)d_out;

  char* ws = (char*)d_ws;
  ushort* hT   = (ushort*)(ws);
  ushort* qT2  = (ushort*)(ws + (4u << 20));
  ushort* kT2  = (ushort*)(ws + (8u << 20));
  ushort* vN   = (ushort*)(ws + (12u << 20));
  ushort* aoT  = (ushort*)(ws + (16u << 20));
  float2* part = (float2*)(ws + (20u << 20));

  void* args[] = {
    (void*)&x, (void*)&gns, (void*)&gnb, (void*)&wqkv, (void*)&bqkv,
    (void*)&wout, (void*)&bout, (void*)&out, (void*)&hT, (void*)&qT2,
    (void*)&kT2, (void*)&vN, (void*)&aoT, (void*)&part
  };
  hipLaunchCooperativeKernel((const void*)fused_kernel, dim3(512), dim3(256),
                             args, 0, stream);
}

// Round 9
// 182.794 us; speedup vs baseline: 1.8782x; 1.8782x over previous
//
#include <hip/hip_runtime.h>
#include <hip/hip_bf16.h>
#include <math.h>

// Problem constants
#define BB 8
#define CC 256
#define NN 1024     // H*W
#define HEADS 8
#define HDIM 32
#define NGRP 8

using bf16x8 = __attribute__((ext_vector_type(8))) short;
using f32x4  = __attribute__((ext_vector_type(4))) float;

#if __has_builtin(__builtin_amdgcn_exp2f)
#define EXP2(x) __builtin_amdgcn_exp2f(x)
#else
#define EXP2(x) exp2f(x)
#endif

// 1/sqrt(32) * log2(e): folded into Q so softmax exp is native v_exp_f32
#define SCL_Q_LOG2E 0.2550348892803828f

static __device__ __forceinline__ ushort f2bf(float x) {
  union { __hip_bfloat16 b; ushort u; } c;
  c.b = __float2bfloat16(x);   // RNE
  return c.u;
}

// ---------------------------------------------------------------------------
// GN pass 1: partial sum/sumsq. 1024 blocks x 256 thr, 2 float4/thread.
// ---------------------------------------------------------------------------
__global__ __launch_bounds__(256) void gn_stats1(
    const float* __restrict__ x, float2* __restrict__ part)
{
  const int p = blockIdx.x, t = threadIdx.x;
  const float4* src = (const float4*)x + (size_t)p * 512;
  const float4 a = src[t], b = src[t + 256];
  float s  = a.x + a.y + a.z + a.w + b.x + b.y + b.z + b.w;
  float ss = a.x*a.x + a.y*a.y + a.z*a.z + a.w*a.w
           + b.x*b.x + b.y*b.y + b.z*b.z + b.w*b.w;
#pragma unroll
  for (int off = 32; off > 0; off >>= 1) {
    s  += __shfl_down(s, off);
    ss += __shfl_down(ss, off);
  }
  __shared__ float rs[4], rss[4];
  const int wid = t >> 6, lane = t & 63;
  if (lane == 0) { rs[wid] = s; rss[wid] = ss; }
  __syncthreads();
  if (t == 0) {
    float2 o;
    o.x = rs[0] + rs[1] + rs[2] + rs[3];
    o.y = rss[0] + rss[1] + rss[2] + rss[3];
    part[p] = o;
  }
}

// ---------------------------------------------------------------------------
// GN apply + transpose (stats2 fused): x[b][c][n] fp32 -> hT[b][n][c] bf16.
// ---------------------------------------------------------------------------
__global__ __launch_bounds__(256) void gnt_kernel(
    const float* __restrict__ x, const float2* __restrict__ part,
    const float* __restrict__ gns, const float* __restrict__ gnb,
    ushort* __restrict__ hT)
{
  __shared__ ushort Ls[64 * 68];  // [n][c] pitch 68
  __shared__ float2 gstat[2];
  const int t = threadIdx.x;
  const int b = blockIdx.z;
  const int c0 = blockIdx.y << 6, n0 = blockIdx.x << 6;

  if (t < 32) {
    const int gsel = t >> 4, ci = t & 15;
    const float2 pp = part[((b * 8) + (blockIdx.y << 1) + gsel) * 16 + ci];
    float s = pp.x, ss = pp.y;
#pragma unroll
    for (int off = 8; off > 0; off >>= 1) {
      s  += __shfl_down(s, off, 16);
      ss += __shfl_down(ss, off, 16);
    }
    if (ci == 0) {
      const float mean = s * (1.f / 32768.f);
      const float var = ss * (1.f / 32768.f) - mean * mean;
      float2 o; o.x = mean; o.y = rsqrtf(var + 1e-5f);
      gstat[gsel] = o;
    }
  }
  __syncthreads();

#pragma unroll
  for (int li = 0; li < 4; ++li) {
    const int id = t + (li << 8);          // 0..1023
    const int row = id >> 4, col4 = id & 15;
    const int c = c0 + row;
    const float2 st = gstat[row >> 5];
    const float sc = gns[c] * st.y;
    const float sh = gnb[c] - st.x * sc;
    const float4 v = *(const float4*)(x + ((size_t)b * CC + c) * NN + n0 + col4 * 4);
    const int nb = col4 * 4;
    Ls[(nb + 0) * 68 + row] = f2bf(v.x * sc + sh);
    Ls[(nb + 1) * 68 + row] = f2bf(v.y * sc + sh);
    Ls[(nb + 2) * 68 + row] = f2bf(v.z * sc + sh);
    Ls[(nb + 3) * 68 + row] = f2bf(v.w * sc + sh);
  }
  __syncthreads();
#pragma unroll
  for (int li = 0; li < 2; ++li) {
    const int id = t + (li << 8);          // 0..511
    const int nR = id >> 3, cP = id & 7;
    union { uint4 v; ushort4 s[2]; } ov;
    ov.s[0] = *(const ushort4*)&Ls[nR * 68 + cP * 8];
    ov.s[1] = *(const ushort4*)&Ls[nR * 68 + cP * 8 + 4];
    *(uint4*)(hT + ((size_t)b * NN + n0 + nR) * CC + c0 + cP * 8) = ov.v;
  }
}

// ---------------------------------------------------------------------------
// Convs: bf16 MFMA GEMM (R7-identical math). REP repeats the whole
// k-loop+epilogue for PROFILING ATTRIBUTION (idempotent re-writes).
// ---------------------------------------------------------------------------
template <int MODE, int REP>
__global__ __launch_bounds__(256) void conv_mfma_kernel(
    const float* __restrict__ W32, const float* __restrict__ bias,
    const ushort* __restrict__ X, const float* __restrict__ xres,
    ushort* __restrict__ qT2, ushort* __restrict__ kT2, ushort* __restrict__ vN,
    float* __restrict__ out)
{
  const int t = threadIdx.x;
  const int w = t >> 6, l = t & 63;
  const int lg = l >> 4, lr = l & 15;
  const int wr = w >> 1, wc = w & 1;
  const int b = blockIdx.z;
  const int o0 = blockIdx.y << 6, n0 = blockIdx.x << 6;

  __shared__ ushort Ws[64][72];  // [o][k]
  __shared__ ushort Xs[64][72];  // [n][k]

  union FragU { ushort4 u[2]; bf16x8 f; };
  const ushort* Xb = X + (size_t)b * 1024 * 256;

#pragma unroll 1
  for (int rep = 0; rep < REP; ++rep) {
    f32x4 acc[2][2] = {};  // [ms(o)][ns(n)]

    for (int k0 = 0; k0 < 256; k0 += 64) {
      __syncthreads();
#pragma unroll
      for (int li = 0; li < 2; ++li) {
        const int id = t + (li << 8);       // 0..511
        const int rr = id >> 3, c8 = id & 7;
        const float* wsrc = W32 + (size_t)(o0 + rr) * 256 + k0 + c8 * 8;
        const float4 wa = *(const float4*)wsrc;
        const float4 wb = *(const float4*)(wsrc + 4);
        union { uint4 v; ushort s[8]; } wv;
        wv.s[0] = f2bf(wa.x); wv.s[1] = f2bf(wa.y); wv.s[2] = f2bf(wa.z); wv.s[3] = f2bf(wa.w);
        wv.s[4] = f2bf(wb.x); wv.s[5] = f2bf(wb.y); wv.s[6] = f2bf(wb.z); wv.s[7] = f2bf(wb.w);
        *(uint4*)&Ws[rr][c8 * 8] = wv.v;
        const uint4 xv = *(const uint4*)(Xb + (size_t)(n0 + rr) * 256 + k0 + c8 * 8);
        *(uint4*)&Xs[rr][c8 * 8] = xv;
      }
      __syncthreads();

      FragU af[2][2], xf[2][2];  // [ms|ns][kc]
#pragma unroll
      for (int i = 0; i < 2; ++i)
#pragma unroll
        for (int kc = 0; kc < 2; ++kc) {
          const ushort* p = &Ws[wr * 32 + i * 16 + lr][kc * 32 + lg * 4];
          af[i][kc].u[0] = *(const ushort4*)p;
          af[i][kc].u[1] = *(const ushort4*)(p + 16);
          const ushort* q = &Xs[wc * 32 + i * 16 + lr][kc * 32 + lg * 4];
          xf[i][kc].u[0] = *(const ushort4*)q;
          xf[i][kc].u[1] = *(const ushort4*)(q + 16);
        }
#pragma unroll
      for (int ms = 0; ms < 2; ++ms)
#pragma unroll
        for (int ns = 0; ns < 2; ++ns) {
          acc[ms][ns] = __builtin_amdgcn_mfma_f32_16x16x32_bf16(af[ms][0].f, xf[ns][0].f, acc[ms][ns], 0, 0, 0);
          acc[ms][ns] = __builtin_amdgcn_mfma_f32_16x16x32_bf16(af[ms][1].f, xf[ns][1].f, acc[ms][ns], 0, 0, 0);
        }
    }

    // Epilogue. D frag: row(o) = lg*4 + reg, col(n) = lr (within 16x16).
    if (MODE == 0) {
      const int sec = o0 >> 8;               // 0=Q, 1=K, 2=V
      const int oin = o0 & 255;
      const float scl = (sec == 0) ? SCL_Q_LOG2E : 1.0f;
      ushort* Lp = &Xs[0][0];
      __syncthreads();
#pragma unroll
      for (int ms = 0; ms < 2; ++ms) {
        const int ob = o0 + wr * 32 + ms * 16 + lg * 4;
        const float4 b4 = *(const float4*)(bias + ob);
        const int ol = wr * 32 + ms * 16 + lg * 4;
#pragma unroll
        for (int ns = 0; ns < 2; ++ns) {
          const int nl = wc * 32 + ns * 16 + lr;
          Lp[(ol + 0) * 68 + nl] = f2bf((acc[ms][ns][0] + b4.x) * scl);
          Lp[(ol + 1) * 68 + nl] = f2bf((acc[ms][ns][1] + b4.y) * scl);
          Lp[(ol + 2) * 68 + nl] = f2bf((acc[ms][ns][2] + b4.z) * scl);
          Lp[(ol + 3) * 68 + nl] = f2bf((acc[ms][ns][3] + b4.w) * scl);
        }
      }
      __syncthreads();
      if (sec < 2) {
        ushort* dst = (sec == 0) ? qT2 : kT2;
        const int nl = t & 63, hd = t >> 6;
        const int hl = hd >> 1, dh = hd & 1;
        const int bh = b * 8 + (oin >> 5) + hl;
        union { uint4 v[2]; ushort s[16]; } o;
#pragma unroll
        for (int j = 0; j < 16; ++j)
          o.s[j] = Lp[(hl * 32 + dh * 16 + j) * 68 + nl];
        uint4* dp = (uint4*)(dst + (((size_t)bh * 2 + dh) * 1024 + n0 + nl) * 16);
        dp[0] = o.v[0];
        dp[1] = o.v[1];
      } else {
        const int r = t >> 2, p = t & 3;
        const int oo = oin + r, hh = oo >> 5, d0 = oo & 31;
        union { uint4 v[2]; ushort4 s[4]; } o;
#pragma unroll
        for (int j = 0; j < 4; ++j)
          o.s[j] = *(const ushort4*)&Lp[r * 68 + p * 16 + j * 4];
        uint4* dp = (uint4*)(vN + (((size_t)b * 8 + hh) * 32 + d0) * 1024 + n0 + p * 16);
        dp[0] = o.v[0];
        dp[1] = o.v[1];
      }
    } else {
#pragma unroll
      for (int ms = 0; ms < 2; ++ms) {
        const int ob = o0 + wr * 32 + ms * 16 + lg * 4;
        const float4 b4 = *(const float4*)(bias + ob);
#pragma unroll
        for (int ns = 0; ns < 2; ++ns) {
          const int n = n0 + wc * 32 + ns * 16 + lr;
          const size_t i0 = ((size_t)b * 256 + ob) * 1024 + n;
          out[i0]          = acc[ms][ns][0] + b4.x + xres[i0];
          out[i0 + 1024]   = acc[ms][ns][1] + b4.y + xres[i0 + 1024];
          out[i0 + 2048]   = acc[ms][ns][2] + b4.z + xres[i0 + 2048];
          out[i0 + 3072]   = acc[ms][ns][3] + b4.w + xres[i0 + 3072];
        }
      }
    }
  }
}

// ---------------------------------------------------------------------------
// Attention (R7-identical math), REP-repeated for profiling attribution.
// 2 waves x 32 q-cols, KVBLK=64, direct exp2 softmax. Grid (16,64), block 128.
// ---------------------------------------------------------------------------
template <int REP>
__global__ __launch_bounds__(128) void attn_kernel(
    const ushort* __restrict__ qT2, const ushort* __restrict__ kT2,
    const ushort* __restrict__ vN, ushort* __restrict__ aoT)
{
  const int t = threadIdx.x;
  const int w = t >> 6, l = t & 63;
  const int lg = l >> 4, lr = l & 15;
  const int bh = blockIdx.y;
  const int b = bh >> 3, hh = bh & 7;
  const int qbase = blockIdx.x << 6;

  __shared__ ushort Ks[64][40];   // [m][d]  pitch 80 B
  __shared__ ushort Vs[32][72];   // [d][m]  pitch 144 B

  union FragU { ushort4 u[2]; bf16x8 f; };

  const ushort* Qb2 = qT2 + (size_t)bh * 2 * 1024 * 16;
  const ushort* Kb2 = kT2 + (size_t)bh * 2 * 1024 * 16;
  const ushort* Vbh = vN + (size_t)bh * 32 * 1024;

  FragU qf[2];
#pragma unroll
  for (int qh = 0; qh < 2; ++qh) {
    const int qn = qbase + w * 32 + qh * 16 + lr;
    qf[qh].u[0] = *(const ushort4*)(Qb2 + (size_t)qn * 16 + lg * 4);
    qf[qh].u[1] = *(const ushort4*)(Qb2 + (size_t)(1024 + qn) * 16 + lg * 4);
  }

  const int km = t >> 1, kh = t & 1;
  const ushort* kbase = Kb2 + ((size_t)kh * 1024 + km) * 16;
  const int vd = t >> 2, vp = (t & 3) * 16;
  const ushort* vbase = Vbh + (size_t)vd * 1024 + vp;

#pragma unroll 1
  for (int rep = 0; rep < REP; ++rep) {
    f32x4 accO[2][2] = {};          // [qh][dt]
    float lsum0 = 0.f, lsum1 = 0.f;

    uint4 kr0 = *(const uint4*)kbase;
    uint4 kr1 = *(const uint4*)(kbase + 8);
    uint4 vr0 = *(const uint4*)vbase;
    uint4 vr1 = *(const uint4*)(vbase + 8);

    for (int m0 = 0; m0 < NN; m0 += 64) {
      __syncthreads();
      *(uint4*)&Ks[km][kh * 16] = kr0;
      *(uint4*)&Ks[km][kh * 16 + 8] = kr1;
      *(uint4*)&Vs[vd][vp] = vr0;
      *(uint4*)&Vs[vd][vp + 8] = vr1;
      __syncthreads();

      if (m0 + 64 < NN) {
        const ushort* kn = kbase + (size_t)(m0 + 64) * 16;
        kr0 = *(const uint4*)kn;
        kr1 = *(const uint4*)(kn + 8);
        const ushort* vn2 = vbase + (m0 + 64);
        vr0 = *(const uint4*)vn2;
        vr1 = *(const uint4*)(vn2 + 8);
      }

      // S^T = K . Q^T : 4 m-subtiles x 2 q-halves; K-frag shared.
      f32x4 s[4][2];
#pragma unroll
      for (int ms = 0; ms < 4; ++ms) {
        FragU kf;
        const ushort* kp = &Ks[ms * 16 + lr][lg * 4];
        kf.u[0] = *(const ushort4*)kp;
        kf.u[1] = *(const ushort4*)(kp + 16);
        f32x4 z = {0.f, 0.f, 0.f, 0.f};
        s[ms][0] = __builtin_amdgcn_mfma_f32_16x16x32_bf16(kf.f, qf[0].f, z, 0, 0, 0);
        s[ms][1] = __builtin_amdgcn_mfma_f32_16x16x32_bf16(kf.f, qf[1].f, z, 0, 0, 0);
      }

      // p = exp2(S); accumulate l; pack bf16 B-frags. No cross-lane ops.
      bf16x8 pb[2][2];  // [qh][mc]
#pragma unroll
      for (int mc = 0; mc < 2; ++mc) {
        bf16x8 f0, f1;
#pragma unroll
        for (int r = 0; r < 4; ++r) {
          const float a0 = EXP2(s[2 * mc][0][r]);
          const float a1 = EXP2(s[2 * mc + 1][0][r]);
          const float b0 = EXP2(s[2 * mc][1][r]);
          const float b1 = EXP2(s[2 * mc + 1][1][r]);
          lsum0 += a0 + a1;
          lsum1 += b0 + b1;
          f0[r] = (short)f2bf(a0); f0[r + 4] = (short)f2bf(a1);
          f1[r] = (short)f2bf(b0); f1[r + 4] = (short)f2bf(b1);
        }
        pb[0][mc] = f0;
        pb[1][mc] = f1;
      }

      // PV: O^T[d][n] += V[d][m] . P^T[m][n]; V-frag shared by both qh.
#pragma unroll
      for (int dt = 0; dt < 2; ++dt) {
#pragma unroll
        for (int mc = 0; mc < 2; ++mc) {
          FragU vf;
          const ushort* vpp = &Vs[dt * 16 + lr][mc * 32 + lg * 4];
          vf.u[0] = *(const ushort4*)vpp;
          vf.u[1] = *(const ushort4*)(vpp + 16);
          accO[0][dt] = __builtin_amdgcn_mfma_f32_16x16x32_bf16(vf.f, pb[0][mc], accO[0][dt], 0, 0, 0);
          accO[1][dt] = __builtin_amdgcn_mfma_f32_16x16x32_bf16(vf.f, pb[1][mc], accO[1][dt], 0, 0, 0);
        }
      }
    }

    lsum0 += __shfl_xor(lsum0, 16); lsum0 += __shfl_xor(lsum0, 32);
    lsum1 += __shfl_xor(lsum1, 16); lsum1 += __shfl_xor(lsum1, 32);
    const float inv0 = 1.f / lsum0, inv1 = 1.f / lsum1;

    // Epilogue: bounce through LDS (reuse Ks; pitch 36) -> coalesced stores.
    ushort* Lb = &Ks[0][0];
    __syncthreads();
#pragma unroll
    for (int dt = 0; dt < 2; ++dt)
#pragma unroll
      for (int r = 0; r < 4; ++r) {
        Lb[(w * 32 + lr) * 36 + dt * 16 + lg * 4 + r]      = f2bf(accO[0][dt][r] * inv0);
        Lb[(w * 32 + 16 + lr) * 36 + dt * 16 + lg * 4 + r] = f2bf(accO[1][dt][r] * inv1);
      }
    __syncthreads();
    {
      const int nl = t >> 1, pp = (t & 1) * 16;
      union { uint4 v[2]; ushort4 s[4]; } o;
#pragma unroll
      for (int j = 0; j < 4; ++j)
        o.s[j] = *(const ushort4*)&Lb[nl * 36 + pp + j * 4];
      uint4* dp = (uint4*)(aoT + ((size_t)b * 1024 + qbase + nl) * 256 + hh * 32 + pp);
      dp[0] = o.v[0];
      dp[1] = o.v[1];
    }
  }
}

// ---------------------------------------------------------------------------
// Launch. ws layout (MB offsets):
//   hT @0 | qT2 @4 | kT2 @8 | vN @12 | aoT @16 | part @20 (8 KB)
// DIAGNOSTIC ROUND: attn x3, conv<0> x4, conv<1> x5 internal repeats to
// surface them in rocprof top-5 (above the 44us fill cutoff).
// ---------------------------------------------------------------------------
extern "C" void kernel_launch(void* const* d_in, const int* in_sizes, int n_in,
                              void* d_out, int out_size, void* d_ws, size_t ws_size,
                              hipStream_t stream)
{
  const float* x    = (const float*)d_in[0];
  const float* gns  = (const float*)d_in[1];
  const float* gnb  = (const float*)d_in[2];
  const float* wqkv = (const float*)d_in[3];
  const float* bqkv = (const float*)d_in[4];
  const float* wout = (const float*)d_in[5];
  const float* bout = (const float*)d_in[6];
  float* out = (float*)d_out;

  char* ws = (char*)d_ws;
  ushort* hT   = (ushort*)(ws);
  ushort* qT2  = (ushort*)(ws + (4u << 20));
  ushort* kT2  = (ushort*)(ws + (8u << 20));
  ushort* vN   = (ushort*)(ws + (12u << 20));
  ushort* aoT  = (ushort*)(ws + (16u << 20));
  float2* part = (float2*)(ws + (20u << 20));

  gn_stats1<<<dim3(1024), dim3(256), 0, stream>>>(x, part);
  gnt_kernel<<<dim3(16, 4, 8), dim3(256), 0, stream>>>(x, part, gns, gnb, hT);
  conv_mfma_kernel<0, 4><<<dim3(16, 12, 8), dim3(256), 0, stream>>>(
      wqkv, bqkv, hT, nullptr, qT2, kT2, vN, nullptr);
  attn_kernel<3><<<dim3(16, 64), dim3(128), 0, stream>>>(qT2, kT2, vN, aoT);
  conv_mfma_kernel<1, 5><<<dim3(16, 4, 8), dim3(256), 0, stream>>>(
      wout, bout, aoT, x, nullptr, nullptr, nullptr, out);
}